// Round 1
// baseline (1402.967 us; speedup 1.0000x reference)
//
#include <hip/hip_runtime.h>

#define D_FEAT 128

// ---------------------------------------------------------------------------
// Kernel 1: edge scatter. 32 threads per edge; each thread handles a float4
// (4 columns). Gather input[edge_col] (coalesced 512B per edge), scale by
// edge weight, atomicAdd into acc[edge_row].
// ---------------------------------------------------------------------------
__global__ __launch_bounds__(256) void scatter_kernel(
    const float* __restrict__ input,
    const int* __restrict__ erow,
    const int* __restrict__ ecol,
    const float* __restrict__ ew,
    float* __restrict__ acc,
    int n_edges)
{
    int t = blockIdx.x * 256 + threadIdx.x;
    int e = t >> 5;                 // 32 threads per edge
    if (e >= n_edges) return;
    int c = (t & 31) << 2;          // columns c..c+3

    int row = erow[e];
    int col = ecol[e];
    float w = ew[e];

    const float4 v = *reinterpret_cast<const float4*>(input + (size_t)col * D_FEAT + c);
    float* dst = acc + (size_t)row * D_FEAT + c;
    atomicAdd(dst + 0, w * v.x);
    atomicAdd(dst + 1, w * v.y);
    atomicAdd(dst + 2, w * v.z);
    atomicAdd(dst + 3, w * v.w);
}

// ---------------------------------------------------------------------------
// Kernel 2: fused support + GEMM + residual.
// Block = 128 threads; thread j owns output column j and keeps W[:,j] in
// 128 VGPRs (fully unrolled loads -> registers). Per row: stage support row
// in LDS, broadcast-read as float4, 128 FMAs, write
//   out = theta*(s@W) + (1-theta)*s + input.
// ---------------------------------------------------------------------------
__global__ __launch_bounds__(128) void fused_kernel(
    const float* __restrict__ acc,
    const float* __restrict__ h0,
    const float* __restrict__ input,
    const float* __restrict__ W,
    float* __restrict__ out,
    const float* __restrict__ lamda_p,
    const float* __restrict__ alpha_p,
    const int* __restrict__ l_p,
    int n_rows, int iters)
{
    __shared__ float s_lds[D_FEAT];
    const int j = threadIdx.x;

    float wcol[D_FEAT];
#pragma unroll
    for (int k = 0; k < D_FEAT; ++k) wcol[k] = W[k * D_FEAT + j];

    const float alpha = alpha_p[0];
    const float lamda = lamda_p[0];
    const float theta = fminf(1.0f, logf(lamda / (float)l_p[0] + 1.0f));
    const float om_alpha = 1.0f - alpha;
    const float om_theta = 1.0f - theta;

    const int stride = gridDim.x;
    for (int it = 0; it < iters; ++it) {
        const int row = blockIdx.x + it * stride;
        const bool active = row < n_rows;
        float sj = 0.0f;
        if (active) {
            const size_t base = (size_t)row * D_FEAT + j;
            sj = fmaf(om_alpha, acc[base], alpha * h0[base]);
            s_lds[j] = sj;
        }
        __syncthreads();
        if (active) {
            float dot = 0.0f;
            const float4* s4 = reinterpret_cast<const float4*>(s_lds);
#pragma unroll
            for (int k4 = 0; k4 < D_FEAT / 4; ++k4) {
                const float4 sv = s4[k4];
                dot = fmaf(sv.x, wcol[4 * k4 + 0], dot);
                dot = fmaf(sv.y, wcol[4 * k4 + 1], dot);
                dot = fmaf(sv.z, wcol[4 * k4 + 2], dot);
                dot = fmaf(sv.w, wcol[4 * k4 + 3], dot);
            }
            const size_t base = (size_t)row * D_FEAT + j;
            out[base] = fmaf(theta, dot, om_theta * sj) + input[base];
        }
        __syncthreads();
    }
}

extern "C" void kernel_launch(void* const* d_in, const int* in_sizes, int n_in,
                              void* d_out, int out_size, void* d_ws, size_t ws_size,
                              hipStream_t stream)
{
    const float* input = (const float*)d_in[0];
    const float* h0    = (const float*)d_in[1];
    const float* W     = (const float*)d_in[2];
    const int*   erow  = (const int*)d_in[3];
    const int*   ecol  = (const int*)d_in[4];
    const float* ew    = (const float*)d_in[5];
    const float* lamda = (const float*)d_in[6];
    const float* alpha = (const float*)d_in[7];
    const int*   l_p   = (const int*)d_in[8];
    float* out = (float*)d_out;

    const int n_nodes = in_sizes[0] / D_FEAT;   // 50000
    const int n_edges = in_sizes[3];            // 800000

    float* acc = (float*)d_ws;
    const size_t acc_bytes = (size_t)n_nodes * D_FEAT * sizeof(float);
    hipMemsetAsync(acc, 0, acc_bytes, stream);

    {
        long long threads = (long long)n_edges * 32;
        int blocks = (int)((threads + 255) / 256);
        scatter_kernel<<<blocks, 256, 0, stream>>>(input, erow, ecol, ew, acc, n_edges);
    }
    {
        int grid = 1024;
        int iters = (n_nodes + grid - 1) / grid;
        fused_kernel<<<grid, 128, 0, stream>>>(acc, h0, input, W, out,
                                               lamda, alpha, l_p, n_nodes, iters);
    }
}

// Round 2
// 224.032 us; speedup vs baseline: 6.2623x; 6.2623x over previous
//
#include <hip/hip_runtime.h>

#define D_FEAT 128

// ============================================================================
// Stage 1: device-side CSR build (counting sort by edge_row).
//   hist -> per-chunk partial sums -> scan partials -> per-chunk scan ->
//   scatter edges into (scol, sw) sorted by row.
// Only int atomics (1.6M total) instead of 102.4M fp32 atomics.
// ============================================================================

__global__ __launch_bounds__(256) void hist_kernel(
    const int* __restrict__ erow, int* __restrict__ cnt, int n_edges)
{
    int e = blockIdx.x * 256 + threadIdx.x;
    if (e < n_edges) atomicAdd(&cnt[erow[e]], 1);
}

__global__ __launch_bounds__(256) void partial_kernel(
    const int* __restrict__ cnt, int* __restrict__ partial, int n)
{
    __shared__ int lds[4];
    int i = blockIdx.x * 256 + threadIdx.x;
    int v = (i < n) ? cnt[i] : 0;
#pragma unroll
    for (int off = 32; off > 0; off >>= 1) v += __shfl_down(v, off, 64);
    if ((threadIdx.x & 63) == 0) lds[threadIdx.x >> 6] = v;
    __syncthreads();
    if (threadIdx.x == 0)
        partial[blockIdx.x] = lds[0] + lds[1] + lds[2] + lds[3];
}

// single block; nb <= 256 (N=50000 -> nb=196)
__global__ __launch_bounds__(256) void scan_partial_kernel(
    int* __restrict__ partial, int nb)
{
    __shared__ int lds[256];
    int t = threadIdx.x;
    int v = (t < nb) ? partial[t] : 0;
    lds[t] = v;
    __syncthreads();
#pragma unroll
    for (int off = 1; off < 256; off <<= 1) {
        int add = (t >= off) ? lds[t - off] : 0;
        __syncthreads();
        lds[t] += add;
        __syncthreads();
    }
    if (t < nb) partial[t] = lds[t] - v;   // exclusive prefix of chunk sums
}

__global__ __launch_bounds__(256) void scan_final_kernel(
    const int* __restrict__ cnt, const int* __restrict__ partial,
    int* __restrict__ offs, int* __restrict__ cursor, int n)
{
    __shared__ int lds[256];
    int t = threadIdx.x;
    int i = blockIdx.x * 256 + t;
    int v = (i < n) ? cnt[i] : 0;
    lds[t] = v;
    __syncthreads();
#pragma unroll
    for (int off = 1; off < 256; off <<= 1) {
        int add = (t >= off) ? lds[t - off] : 0;
        __syncthreads();
        lds[t] += add;
        __syncthreads();
    }
    if (i < n) {
        int ex = lds[t] - v + partial[blockIdx.x];
        offs[i] = ex;
        cursor[i] = ex;
    }
}

__global__ __launch_bounds__(256) void edge_scatter_kernel(
    const int* __restrict__ erow, const int* __restrict__ ecol,
    const float* __restrict__ ew, int* __restrict__ cursor,
    int* __restrict__ scol, float* __restrict__ sw, int n_edges)
{
    int e = blockIdx.x * 256 + threadIdx.x;
    if (e >= n_edges) return;
    int r = erow[e];
    int pos = atomicAdd(&cursor[r], 1);
    scol[pos] = ecol[e];
    sw[pos]   = ew[e];
}

// ============================================================================
// Stage 2: CSR SpMM + support blend. One wave per row; lane owns 2 columns
// (float2). Per edge: coalesced 512B read of input[col], fma by weight.
// Epilogue: support = (1-alpha)*hi + alpha*h0, written to d_out (reused as
// the support buffer; kernel 3 rewrites d_out in place).
// ============================================================================
__global__ __launch_bounds__(256) void spmm_kernel(
    const float* __restrict__ input, const float* __restrict__ h0,
    const int* __restrict__ offs, const int* __restrict__ cnt,
    const int* __restrict__ scol, const float* __restrict__ sw,
    const float* __restrict__ alpha_p, float* __restrict__ outp, int n)
{
    int lane = threadIdx.x & 63;
    int row  = blockIdx.x * 4 + (threadIdx.x >> 6);
    if (row >= n) return;

    int beg = __builtin_amdgcn_readfirstlane(offs[row]);
    int deg = __builtin_amdgcn_readfirstlane(cnt[row]);

    const float2* in2 = reinterpret_cast<const float2*>(input);
    float2 acc = make_float2(0.0f, 0.0f);
    for (int e = 0; e < deg; ++e) {
        int   c = scol[beg + e];
        float w = sw[beg + e];
        float2 v = in2[(size_t)c * 64 + lane];
        acc.x = fmaf(w, v.x, acc.x);
        acc.y = fmaf(w, v.y, acc.y);
    }

    const float alpha = alpha_p[0];
    const float oma   = 1.0f - alpha;
    float2 h = reinterpret_cast<const float2*>(h0)[(size_t)row * 64 + lane];
    float2 s;
    s.x = fmaf(oma, acc.x, alpha * h.x);
    s.y = fmaf(oma, acc.y, alpha * h.y);
    reinterpret_cast<float2*>(outp)[(size_t)row * 64 + lane] = s;
}

// ============================================================================
// Stage 3: fused GEMM + blend + residual, in place on d_out.
// Thread j holds W[:,j] in 128 VGPRs; per row stage support in LDS,
// out = theta*(s@W) + (1-theta)*s + input.
// ============================================================================
__global__ __launch_bounds__(128) void fused_kernel(
    float* __restrict__ io, const float* __restrict__ input,
    const float* __restrict__ W,
    const float* __restrict__ lamda_p, const int* __restrict__ l_p,
    int n_rows, int iters)
{
    __shared__ float s_lds[D_FEAT];
    const int j = threadIdx.x;

    float wcol[D_FEAT];
#pragma unroll
    for (int k = 0; k < D_FEAT; ++k) wcol[k] = W[k * D_FEAT + j];

    const float lamda = lamda_p[0];
    const float theta = fminf(1.0f, logf(lamda / (float)l_p[0] + 1.0f));
    const float om_theta = 1.0f - theta;

    const int stride = gridDim.x;
    for (int it = 0; it < iters; ++it) {
        const int row = blockIdx.x + it * stride;
        const bool active = row < n_rows;
        float sj = 0.0f;
        if (active) {
            sj = io[(size_t)row * D_FEAT + j];
            s_lds[j] = sj;
        }
        __syncthreads();
        if (active) {
            float dot = 0.0f;
            const float4* s4 = reinterpret_cast<const float4*>(s_lds);
#pragma unroll
            for (int k4 = 0; k4 < D_FEAT / 4; ++k4) {
                const float4 sv = s4[k4];
                dot = fmaf(sv.x, wcol[4 * k4 + 0], dot);
                dot = fmaf(sv.y, wcol[4 * k4 + 1], dot);
                dot = fmaf(sv.z, wcol[4 * k4 + 2], dot);
                dot = fmaf(sv.w, wcol[4 * k4 + 3], dot);
            }
            const size_t base = (size_t)row * D_FEAT + j;
            io[base] = fmaf(theta, dot, om_theta * sj) + input[base];
        }
        __syncthreads();
    }
}

extern "C" void kernel_launch(void* const* d_in, const int* in_sizes, int n_in,
                              void* d_out, int out_size, void* d_ws, size_t ws_size,
                              hipStream_t stream)
{
    const float* input = (const float*)d_in[0];
    const float* h0    = (const float*)d_in[1];
    const float* W     = (const float*)d_in[2];
    const int*   erow  = (const int*)d_in[3];
    const int*   ecol  = (const int*)d_in[4];
    const float* ew    = (const float*)d_in[5];
    const float* lamda = (const float*)d_in[6];
    const float* alpha = (const float*)d_in[7];
    const int*   l_p   = (const int*)d_in[8];
    float* out = (float*)d_out;

    const int n_nodes = in_sizes[0] / D_FEAT;   // 50000
    const int n_edges = in_sizes[3];            // 800000

    // ---- workspace layout (all 4-byte elems): 3N + 256 + 2E ints ~ 7 MB ----
    int*   cnt     = (int*)d_ws;
    int*   offs    = cnt + n_nodes;
    int*   cursor  = offs + n_nodes;
    int*   partial = cursor + n_nodes;          // 256 slots
    int*   scol    = partial + 256;
    float* sw      = (float*)(scol + n_edges);

    const int nb = (n_nodes + 255) / 256;       // 196 <= 256

    hipMemsetAsync(cnt, 0, (size_t)n_nodes * sizeof(int), stream);

    hist_kernel<<<(n_edges + 255) / 256, 256, 0, stream>>>(erow, cnt, n_edges);
    partial_kernel<<<nb, 256, 0, stream>>>(cnt, partial, n_nodes);
    scan_partial_kernel<<<1, 256, 0, stream>>>(partial, nb);
    scan_final_kernel<<<nb, 256, 0, stream>>>(cnt, partial, offs, cursor, n_nodes);
    edge_scatter_kernel<<<(n_edges + 255) / 256, 256, 0, stream>>>(
        erow, ecol, ew, cursor, scol, sw, n_edges);

    spmm_kernel<<<(n_nodes + 3) / 4, 256, 0, stream>>>(
        input, h0, offs, cnt, scol, sw, alpha, out, n_nodes);

    {
        const int grid = 1024;
        const int iters = (n_nodes + grid - 1) / grid;
        fused_kernel<<<grid, 128, 0, stream>>>(out, input, W, lamda, l_p,
                                               n_nodes, iters);
    }
}